// Round 9
// baseline (1760.108 us; speedup 1.0000x reference)
//
#include <hip/hip_runtime.h>
#include <hip/hip_bf16.h>

typedef __hip_bfloat16 bf16;
typedef __attribute__((ext_vector_type(8))) short short8;
typedef __attribute__((ext_vector_type(4))) float float4v;

#define BSZ 32
#define TT  128
#define IC  16
#define NDIM 512
#define WS_NEED ((size_t)4 * IC * NDIM * NDIM * 2)   // 33.55 MB bf16 packed weights
#define CTR_BYTES 4096
#define HBUF_DW 131072          // dwords per parity: 32*16*512 bf16 = 512 KB
#define WS_TOTAL (WS_NEED + CTR_BYTES + (size_t)2 * HBUF_DW * 4)
#define LDS_BYTES (163840)      // 128 KB weights + 32 KB h

__device__ __forceinline__ float sigf(float v) { return 1.0f / (1.0f + expf(-v)); }
__device__ __forceinline__ float fast_sig(float v) { return 1.0f / (1.0f + __expf(-v)); }
__device__ __forceinline__ float fast_tanh(float v) {
    v = fminf(fmaxf(v, -15.f), 15.f);
    float e = __expf(2.f * v);
    return (e - 1.f) / (e + 1.f);
}
__device__ __forceinline__ unsigned f2bfb(float f) {
    bf16 h = __float2bfloat16(f);
    return (unsigned)*reinterpret_cast<unsigned short*>(&h);
}
// h LDS swizzle (elem units): conflict-free for staging writes and A-frag reads.
__device__ __forceinline__ int hsw(int b, int col) {
    return b * 512 + (col ^ (((b + (col >> 6)) & 7) * 8));
}

// ---------------- one-time weight pack: fp32 W -> bf16 MFMA B-fragments ----
__global__ void pack_w(const float* __restrict__ Wj, const float* __restrict__ Wi,
                       const float* __restrict__ Wf, const float* __restrict__ Wo,
                       uint4* __restrict__ wpk, int* __restrict__ ctr)
{
    __shared__ float tile[NDIM][17];
    const int blk  = blockIdx.x;
    const int nt16 = blk & 31;
    const int i    = (blk >> 5) & 15;
    const int g    = blk >> 9;
    const float* W = (g == 0) ? Wj : (g == 1) ? Wi : (g == 2) ? Wf : Wo;
    const float* base = W + (size_t)i * NDIM * NDIM + nt16 * 16;
    const int tid = threadIdx.x;

    if (blk == 0) { ctr[tid] = 0; ctr[tid + 256] = 0; }   // zero epoch flags

    #pragma unroll
    for (int r = 0; r < 2; r++) {
        int n = tid + r * 256;
        const float4* p = (const float4*)(base + (size_t)n * NDIM);
        float4 v0 = p[0], v1 = p[1], v2 = p[2], v3 = p[3];
        float* d = &tile[n][0];
        d[0]=v0.x; d[1]=v0.y; d[2]=v0.z; d[3]=v0.w;
        d[4]=v1.x; d[5]=v1.y; d[6]=v1.z; d[7]=v1.w;
        d[8]=v2.x; d[9]=v2.y; d[10]=v2.z; d[11]=v2.w;
        d[12]=v3.x; d[13]=v3.y; d[14]=v3.z; d[15]=v3.w;
    }
    __syncthreads();
    #pragma unroll
    for (int p = 0; p < 4; p++) {
        int f = p * 256 + tid;
        int kstep = f >> 6, L = f & 63;
        int quad = L >> 4, col = L & 15;
        int nr = kstep * 32 + quad * 8;
        unsigned u[4];
        #pragma unroll
        for (int w = 0; w < 4; w++) {
            unsigned lo = f2bfb(tile[nr + 2 * w][col]);
            unsigned hi = f2bfb(tile[nr + 2 * w + 1][col]);
            u[w] = lo | (hi << 16);
        }
        wpk[(size_t)blk * 1024 + (size_t)kstep * 64 + L] = make_uint4(u[0], u[1], u[2], u[3]);
    }
}

// ---------------- persistent kernel ----------------------------------------
// h exchange via double-buffered bf16 mailbox (hbuf) with agent-scope relaxed
// atomics: stores write through to LLC (no dirty L2 -> no threadfence/wbl2),
// loads bypass L2 (no buffer_inv). Per-block epoch flags replace the counter
// RMW. Release ordering: __syncthreads drains vmcnt before the flag store.
__launch_bounds__(256)
__global__ void step_persist(
    const float* __restrict__ x,
    const float* __restrict__ Uj, const float* __restrict__ Ui, const float* __restrict__ Uf, const float* __restrict__ Uo,
    const uint4* __restrict__ wpk, int* __restrict__ flags, unsigned* __restrict__ hbuf,
    const float* __restrict__ bj, const float* __restrict__ bi, const float* __restrict__ bfp, const float* __restrict__ bo,
    float* __restrict__ out)
{
    extern __shared__ __align__(16) char smem[];
    uint4* w_s  = (uint4*)smem;                      // [8][1024] uint4 = 128 KB
    bf16*  h_s  = (bf16*)(smem + 131072);            // [32][512] swizzled = 32 KB
    unsigned* hs32 = (unsigned*)h_s;

    const int blk = blockIdx.x;
    const int i   = blk & 15;          // channel (16 blocks/channel land on one XCD under round-robin)
    const int kt  = blk >> 4;          // 32-col tile
    const int tid = threadIdx.x;
    const int wid = tid >> 6, L = tid & 63;
    const int quad = L >> 4, c15 = L & 15;
    const int nt16 = kt * 2 + (wid & 1);
    const int Mh   = (wid >> 1) * 16;

    float* hfin = out + (size_t)BSZ * TT * IC * NDIM;
    float* cfin = hfin + (size_t)BSZ * IC * NDIM;
    int* myflags = flags + i * 16;

    // ---- prologue: weights -> LDS
    #pragma unroll
    for (int pair = 0; pair < 8; pair++) {
        int ntl = pair >> 2, g = pair & 3;
        const uint4* src = wpk + ((size_t)((g * IC + i) * 32 + kt * 2 + ntl)) * 1024;
        uint4* dst = w_s + pair * 1024;
        #pragma unroll
        for (int rep = 0; rep < 4; rep++) dst[rep * 256 + tid] = src[rep * 256 + tid];
    }

    const int n = nt16 * 16 + c15;
    const size_t un = (size_t)i * NDIM + n;
    const float u0 = Uj[un], u1 = Ui[un], u2 = Uf[un], u3 = Uo[un];
    const float cb0 = bj[un], cb1 = bi[un], cb2 = bfp[un], cb3 = bo[un];
    float creg[4] = {0.f, 0.f, 0.f, 0.f};
    const float a_out = 0.990049834f;                // exp(-0.01)

    const int r_    = Mh + c15;
    const int rbase = r_ * 512;
    const int wb    = (wid & 1) * 4096 + L;

    __syncthreads();

    for (int t = 0; t < TT; t++) {
        float4v acc0 = {0,0,0,0}, acc1 = {0,0,0,0}, acc2 = {0,0,0,0}, acc3 = {0,0,0,0};

        // x prefetch (independent of h)
        float xv[4];
        #pragma unroll
        for (int r = 0; r < 4; r++)
            xv[r] = x[(size_t)((Mh + quad * 4 + r) * TT + t) * IC + i];

        if (t > 0) {
            // ---- acquire: lanes 0..15 of wave 0 poll the 16 epoch flags
            if (wid == 0) {
                while (true) {
                    int v = (L < 16)
                        ? __hip_atomic_load(&myflags[L], __ATOMIC_RELAXED, __HIP_MEMORY_SCOPE_AGENT)
                        : t;
                    unsigned long long m = __ballot(v >= t);
                    if (m == ~0ULL) break;
                    __builtin_amdgcn_s_sleep(2);
                }
            }
            __syncthreads();

            // ---- stage h(t-1): bf16 mailbox -> swizzled LDS (pure dword copy)
            {
                const unsigned* hsrc = hbuf + (((t - 1) & 1) ? HBUF_DW : 0);
                #pragma unroll 8
                for (int l = 0; l < 32; l++) {
                    unsigned v = __hip_atomic_load(hsrc + (l * 16 + i) * 256 + tid,
                                                   __ATOMIC_RELAXED, __HIP_MEMORY_SCOPE_AGENT);
                    hs32[l * 256 + (tid ^ (((l + (tid >> 5)) & 7) * 4))] = v;
                }
            }
            __syncthreads();

            // ---- K-loop: LDS-resident weights, 4 gates per ks
            #pragma unroll
            for (int ks = 0; ks < 16; ks++) {
                int acol = (ks * 32 + quad * 8) ^ (((r_ + (ks >> 1)) & 7) * 8);
                short8 a  = *(const short8*)(h_s + rbase + acol);
                short8 b0 = *(const short8*)(w_s + wb + ks * 64);
                short8 b1 = *(const short8*)(w_s + wb + 1024 + ks * 64);
                short8 b2 = *(const short8*)(w_s + wb + 2048 + ks * 64);
                short8 b3 = *(const short8*)(w_s + wb + 3072 + ks * 64);
                acc0 = __builtin_amdgcn_mfma_f32_16x16x32_bf16(a, b0, acc0, 0, 0, 0);
                acc1 = __builtin_amdgcn_mfma_f32_16x16x32_bf16(a, b1, acc1, 0, 0, 0);
                acc2 = __builtin_amdgcn_mfma_f32_16x16x32_bf16(a, b2, acc2, 0, 0, 0);
                acc3 = __builtin_amdgcn_mfma_f32_16x16x32_bf16(a, b3, acc3, 0, 0, 0);
            }
        }

        // ---- epilogue
        unsigned* hdst = hbuf + ((t & 1) ? HBUF_DW : 0);
        #pragma unroll
        for (int r = 0; r < 4; r++) {
            int b = Mh + quad * 4 + r;

            float jg = fast_tanh(acc0[r] + cb0 + xv[r] * u0);
            float ig = fast_sig (acc1[r] + cb1 + xv[r] * u1);
            float fg = fast_sig (acc2[r] + cb2 + xv[r] * u2);
            float og = fast_sig (acc3[r] + cb3 + xv[r] * u3);

            float alpha_m = __expf(-7.8125e-5f * jg);
            float ro      = __expf(-1.5625e-4f * ig);
            float b_ad    = ro * 0.1f + (1.0f - ro) * ig;
            float Bth     = 0.04f + 1.8f * b_ad;

            float hprev = (t > 0) ? __bfloat162float(h_s[hsw(b, n)]) : 0.0f;

            float mem   = jg * alpha_m + (1.0f - alpha_m) * hprev - Bth * ig * 0.01f;
            float spike = (mem - Bth) > 0.0f ? 1.0f : 0.0f;
            float mem_o = mem * a_out + (1.0f - a_out) * spike + 0.08f;

            float cn = creg[r] * fg + ig * spike * mem_o;
            float hn = og * fast_tanh(cn);
            creg[r] = cn;

            out[((size_t)(b * TT + t) * IC + i) * NDIM + n] = hn;   // plain cached store

            // bf16 mailbox: lane pair (c15 even/odd) packs one dword
            unsigned hb = f2bfb(hn);
            unsigned other = __shfl_xor(hb, 1);
            if ((c15 & 1) == 0 && t < TT - 1) {
                unsigned dword = hb | (other << 16);
                __hip_atomic_store(hdst + (b * IC + i) * 256 + (n >> 1), dword,
                                   __ATOMIC_RELAXED, __HIP_MEMORY_SCOPE_AGENT);
            }
            if (t == TT - 1) {
                size_t sidx = ((size_t)b * IC + i) * NDIM + n;
                hfin[sidx] = hn;
                cfin[sidx] = cn;
            }
        }

        // ---- release: epoch flag after all mailbox stores drained
        if (t < TT - 1) {
            __syncthreads();   // emits s_waitcnt vmcnt(0) per wave before barrier
            if (tid == 0)
                __hip_atomic_store(&myflags[kt], t + 1,
                                   __ATOMIC_RELAXED, __HIP_MEMORY_SCOPE_AGENT);
        }
    }
}

// ---------------- fallback tier 1: per-step MFMA (proven R6) ----------------
__launch_bounds__(256)
__global__ void step_mfma(int t,
    const float* __restrict__ x,
    const float* __restrict__ Uj, const float* __restrict__ Ui, const float* __restrict__ Uf, const float* __restrict__ Uo,
    const uint4* __restrict__ wpk,
    const float* __restrict__ bj, const float* __restrict__ bi, const float* __restrict__ bfp, const float* __restrict__ bo,
    float* __restrict__ out)
{
    __shared__ bf16 h_lds[BSZ][NDIM + 8];
    const int i   = blockIdx.x;
    const int kt  = blockIdx.y;
    const int tid = threadIdx.x;
    const int wid = tid >> 6, L = tid & 63;
    const int quad = L >> 4, c15 = L & 15;
    const int nt16 = kt * 2 + (wid & 1);
    const int Mh   = (wid >> 1) * 16;

    float* hfin = out + (size_t)BSZ * TT * IC * NDIM;
    float* cfin = hfin + (size_t)BSZ * IC * NDIM;

    float4v acc0 = {0,0,0,0}, acc1 = {0,0,0,0}, acc2 = {0,0,0,0}, acc3 = {0,0,0,0};

    if (t > 0) {
        {
            int b = tid >> 3, n0 = (tid & 7) * 64;
            const float4* src = (const float4*)(out + ((size_t)(b * TT + (t - 1)) * IC + i) * NDIM + n0);
            #pragma unroll
            for (int q = 0; q < 8; q++) {
                float4 a = src[2 * q], bb = src[2 * q + 1];
                unsigned u0 = f2bfb(a.x) | (f2bfb(a.y) << 16);
                unsigned u1 = f2bfb(a.z) | (f2bfb(a.w) << 16);
                unsigned u2 = f2bfb(bb.x) | (f2bfb(bb.y) << 16);
                unsigned u3 = f2bfb(bb.z) | (f2bfb(bb.w) << 16);
                *(uint4*)&h_lds[b][n0 + q * 8] = make_uint4(u0, u1, u2, u3);
            }
        }
        __syncthreads();

        const size_t gstride = (size_t)IC * 32 * 1024;
        const uint4* bbase = wpk + ((size_t)i * 32 + nt16) * 1024 + L;
        const bf16* arow = &h_lds[Mh + c15][0];

        #pragma unroll 4
        for (int ks = 0; ks < 16; ks++) {
            short8 a  = *(const short8*)(arow + ks * 32 + quad * 8);
            short8 b0 = *(const short8*)(bbase + (size_t)ks * 64);
            short8 b1 = *(const short8*)(bbase + gstride + (size_t)ks * 64);
            short8 b2 = *(const short8*)(bbase + 2 * gstride + (size_t)ks * 64);
            short8 b3 = *(const short8*)(bbase + 3 * gstride + (size_t)ks * 64);
            acc0 = __builtin_amdgcn_mfma_f32_16x16x32_bf16(a, b0, acc0, 0, 0, 0);
            acc1 = __builtin_amdgcn_mfma_f32_16x16x32_bf16(a, b1, acc1, 0, 0, 0);
            acc2 = __builtin_amdgcn_mfma_f32_16x16x32_bf16(a, b2, acc2, 0, 0, 0);
            acc3 = __builtin_amdgcn_mfma_f32_16x16x32_bf16(a, b3, acc3, 0, 0, 0);
        }
    }

    const float a_out = 0.990049834f;
    const int n = nt16 * 16 + c15;
    const size_t un = (size_t)i * NDIM + n;
    float u0 = Uj[un], u1 = Ui[un], u2 = Uf[un], u3 = Uo[un];
    float c0 = bj[un], c1 = bi[un], c2 = bfp[un], c3 = bo[un];

    #pragma unroll
    for (int r = 0; r < 4; r++) {
        int b = Mh + quad * 4 + r;
        size_t sidx = ((size_t)b * IC + i) * NDIM + n;
        float xvv = x[(size_t)(b * TT + t) * IC + i];

        float jg = tanhf(acc0[r] + c0 + xvv * u0);
        float ig = sigf (acc1[r] + c1 + xvv * u1);
        float fg = sigf (acc2[r] + c2 + xvv * u2);
        float og = sigf (acc3[r] + c3 + xvv * u3);

        float alpha_m = expf(-7.8125e-5f * jg);
        float ro      = expf(-1.5625e-4f * ig);
        float b_ad    = ro * 0.1f + (1.0f - ro) * ig;
        float Bth     = 0.04f + 1.8f * b_ad;

        float hprev = 0.0f, cprev = 0.0f;
        if (t > 0) {
            hprev = __bfloat162float(h_lds[b][n]);
            cprev = cfin[sidx];
        }

        float mem   = jg * alpha_m + (1.0f - alpha_m) * hprev - Bth * ig * 0.01f;
        float spike = (mem - Bth) > 0.0f ? 1.0f : 0.0f;
        float mem_o = mem * a_out + (1.0f - a_out) * spike + 0.08f;

        float cn = cprev * fg + ig * spike * mem_o;
        float hn = og * tanhf(cn);

        cfin[sidx] = cn;
        out[((size_t)(b * TT + t) * IC + i) * NDIM + n] = hn;
        if (t == TT - 1) hfin[sidx] = hn;
    }
}

extern "C" void kernel_launch(void* const* d_in, const int* in_sizes, int n_in,
                              void* d_out, int out_size, void* d_ws, size_t ws_size,
                              hipStream_t stream) {
    const float* x   = (const float*)d_in[0];
    const float* Uj  = (const float*)d_in[1];
    const float* Ui_ = (const float*)d_in[2];
    const float* Uf  = (const float*)d_in[3];
    const float* Uo  = (const float*)d_in[4];
    const float* Wj  = (const float*)d_in[5];
    const float* Wi_ = (const float*)d_in[6];
    const float* Wf  = (const float*)d_in[7];
    const float* Wo  = (const float*)d_in[8];
    const float* bj  = (const float*)d_in[9];
    const float* bi_ = (const float*)d_in[10];
    const float* bf_ = (const float*)d_in[11];
    const float* bo  = (const float*)d_in[12];
    float* out = (float*)d_out;

    bool persist_ok = (ws_size >= WS_TOTAL);
    if (persist_ok) {
        hipError_t e = hipFuncSetAttribute(
            reinterpret_cast<const void*>(step_persist),
            hipFuncAttributeMaxDynamicSharedMemorySize, LDS_BYTES);
        if (e != hipSuccess) persist_ok = false;
    }

    if (persist_ok) {
        int* flags = (int*)((char*)d_ws + WS_NEED);
        unsigned* hbuf = (unsigned*)((char*)d_ws + WS_NEED + CTR_BYTES);
        pack_w<<<dim3(2048), dim3(256), 0, stream>>>(Wj, Wi_, Wf, Wo, (uint4*)d_ws, flags);
        step_persist<<<dim3(256), dim3(256), LDS_BYTES, stream>>>(
            x, Uj, Ui_, Uf, Uo, (const uint4*)d_ws, flags, hbuf, bj, bi_, bf_, bo, out);
    } else if (ws_size >= WS_NEED + CTR_BYTES) {
        int* flags = (int*)((char*)d_ws + WS_NEED);
        pack_w<<<dim3(2048), dim3(256), 0, stream>>>(Wj, Wi_, Wf, Wo, (uint4*)d_ws, flags);
        for (int t = 0; t < TT; t++) {
            step_mfma<<<dim3(IC, 16), dim3(256), 0, stream>>>(
                t, x, Uj, Ui_, Uf, Uo, (const uint4*)d_ws, bj, bi_, bf_, bo, out);
        }
    }
}